// Round 5
// baseline (536.511 us; speedup 1.0000x reference)
//
#include <hip/hip_runtime.h>

namespace {

using h16x8 = __attribute__((ext_vector_type(8))) _Float16;
using h16x4 = __attribute__((ext_vector_type(4))) _Float16;
using f32x4 = __attribute__((ext_vector_type(4))) float;

constexpr int kH = 512, kW = 512, kB = 16, kC = 8;
constexpr int kHW = kH * kW;      // per-channel plane
constexpr int kBS = kC * kHW;     // per-batch stride
constexpr int TW = 64, TH = 4;    // pixel tile per 256-thread block; 1 wave per row
constexpr int TWP = TW + 2, THP = TH + 2;
constexpr int SS = 40;            // scratch row stride in halves (80 B, 16B-aligned)

// Kernel 1: count alive cells (x[:,3,:,:] > 0.1). One atomic per block.
__global__ __launch_bounds__(256)
void alive_count_kernel(const float* __restrict__ x, int* __restrict__ cnt) {
    __shared__ int sdata[4];
    const int tid = threadIdx.x;
    const int total4 = kB * kHW / 4;
    int idx = blockIdx.x * 256 + tid;
    const int stride = gridDim.x * 256;
    int local = 0;
    const float4* x4 = (const float4*)x;
    for (int i = idx; i < total4; i += stride) {
        int b = i >> 16;
        int off = i & 65535;
        float4 v = x4[(size_t)b * (kBS / 4) + (3 * kHW / 4) + off];
        local += (v.x > 0.1f) + (v.y > 0.1f) + (v.z > 0.1f) + (v.w > 0.1f);
    }
    for (int off = 32; off > 0; off >>= 1)
        local += __shfl_down(local, off, 64);
    if ((tid & 63) == 0) sdata[tid >> 6] = local;
    __syncthreads();
    if (tid == 0) atomicAdd(cnt, sdata[0] + sdata[1] + sdata[2] + sdata[3]);
}

// Kernel 2: fused NCA step, MLP on the matrix pipe.
// R5: fp16 everywhere in the MLP (mfma_f32_16x16x32_f16). R4's bf16 version
// failed at absmax 0.0386: validated error model says bf16 (eps 2^-9) quant of
// weights+activations across 3 layers * growth 0.3 * 5.9-sigma-of-33M = 0.035.
// fp16 eps 2^-11 cuts that 8x -> ~0.005. Same fragment layouts (C/D layout is
// dtype-independent), cheaper conversions (single v_cvt vs 5-op bf16 RNE).
__global__ __launch_bounds__(256, 3)
void nca_fused_kernel(const float* __restrict__ x,
                      const float* __restrict__ w1, const float* __restrict__ b1,
                      const float* __restrict__ w2, const float* __restrict__ b2,
                      const float* __restrict__ w3, const float* __restrict__ b3,
                      const float* __restrict__ growth,
                      const int* __restrict__ alive_cnt,
                      float* __restrict__ out) {
    __shared__ float tile[kC][THP][TWP];                 // 12672 B
    __shared__ __align__(16) _Float16 scr[4][64 * SS];   // 20480 B

    const int w0 = blockIdx.x * TW;
    const int h0 = blockIdx.y * TH;
    const int b  = blockIdx.z;
    const int tid = threadIdx.x;
    const int wv = tid >> 6;   // wave id == tile row
    const int ln = tid & 63;   // lane == pixel col
    const int lm = ln & 15;
    const int lq = ln >> 4;
    const float* xb = x + (size_t)b * kBS;
    _Float16* base = scr[wv];

    // ---- weight A-fragments: A[m = lm][k = lq*8+j] ----
    h16x8 w1f[2], w2f[2], w3f;
#pragma unroll
    for (int mi = 0; mi < 2; ++mi) {
        int m = mi * 16 + lm;
#pragma unroll
        for (int j = 0; j < 8; ++j) {
            int k = lq * 8 + j;
            w1f[mi][j] = (k < 24) ? (_Float16)w1[m * 24 + k] : (_Float16)0.0f;
            w2f[mi][j] = (_Float16)w2[m * 32 + k];
        }
    }
#pragma unroll
    for (int j = 0; j < 8; ++j)
        w3f[j] = (lm < 8) ? (_Float16)w3[lm * 32 + lq * 8 + j] : (_Float16)0.0f;

    // biases in C/D layout: row m = mi*16 + lq*4 + r
    f32x4 bias1[2], bias2[2], bias3;
#pragma unroll
    for (int mi = 0; mi < 2; ++mi) {
        int m0 = mi * 16 + lq * 4;
#pragma unroll
        for (int r = 0; r < 4; ++r) { bias1[mi][r] = b1[m0 + r]; bias2[mi][r] = b2[m0 + r]; }
    }
#pragma unroll
    for (int r = 0; r < 4; ++r) bias3[r] = (lq < 2) ? b3[lq * 4 + r] : 0.0f;

    // ---- stage input tile + halo (zero pad == SAME conv) ----
    constexpr int TILE_N = kC * THP * TWP;
    for (int i = tid; i < TILE_N; i += 256) {
        int c  = i / (THP * TWP);
        int r  = i - c * (THP * TWP);
        int hh = r / TWP;
        int ww = r - hh * TWP;
        int gh = h0 + hh - 1;
        int gw = w0 + ww - 1;
        float v = 0.0f;
        if ((unsigned)gh < (unsigned)kH && (unsigned)gw < (unsigned)kW)
            v = xb[c * kHW + gh * kW + gw];
        (&tile[0][0][0])[i] = v;
    }
    __syncthreads();

    // ---- perceive -> P chunk vectors (fp16) on the fly; keep only p[0..7] f32 ----
    float pc[8];
    h16x8 vx, vsx, vsy;
    int nalive = 0;
#pragma unroll
    for (int c = 0; c < kC; ++c) {
        float a00 = tile[c][wv    ][ln], a01 = tile[c][wv    ][ln + 1], a02 = tile[c][wv    ][ln + 2];
        float a10 = tile[c][wv + 1][ln], a11 = tile[c][wv + 1][ln + 1], a12 = tile[c][wv + 1][ln + 2];
        float a20 = tile[c][wv + 2][ln], a21 = tile[c][wv + 2][ln + 1], a22 = tile[c][wv + 2][ln + 2];
        pc[c]  = a11;
        vx[c]  = (_Float16)a11;
        vsx[c] = (_Float16)((a02 - a00) + 2.0f * (a12 - a10) + (a22 - a20));
        vsy[c] = (_Float16)((a20 - a00) + 2.0f * (a21 - a01) + (a22 - a02));
        if (c == 3) {
            nalive = (a00 > 0.1f) + (a01 > 0.1f) + (a02 > 0.1f)
                   + (a10 > 0.1f) + (a11 > 0.1f) + (a12 > 0.1f)
                   + (a20 > 0.1f) + (a21 > 0.1f) + (a22 > 0.1f);
        }
    }

    // ---- P -> scratch (B layout: row=pixel, 16B chunk = 8 features, XOR swizzle) ----
    {
        const int sw = (ln >> 2) & 3;
        *(h16x8*)(base + ln * SS + (0 ^ sw) * 8) = vx;
        *(h16x8*)(base + ln * SS + (1 ^ sw) * 8) = vsx;
        *(h16x8*)(base + ln * SS + (2 ^ sw) * 8) = vsy;
        h16x8 z = {};
        *(h16x8*)(base + ln * SS + (3 ^ sw) * 8) = z;  // k=24..31 pad must be clean
    }

    auto readB = [&](int ni) -> h16x8 {
        int row = ni * 16 + lm;
        int phys = lq ^ ((row >> 2) & 3);
        return *(const h16x8*)(base + row * SS + phys * 8);
    };
    auto writeH = [&](int mi, int ni, f32x4 h) {
        int row = ni * 16 + lm;
        int cl = mi * 2 + (lq >> 1);             // logical 16B chunk
        int phys = cl ^ ((row >> 2) & 3);
        h16x4 v;
#pragma unroll
        for (int r = 0; r < 4; ++r) v[r] = (_Float16)h[r];
        *(h16x4*)(base + row * SS + phys * 8 + (lq & 1) * 4) = v;
    };

    h16x8 bfr[4];
    f32x4 acc[2][4];

    // ---- layer 1: C1[32,64] = W1·P + b1, relu ----
#pragma unroll
    for (int ni = 0; ni < 4; ++ni) bfr[ni] = readB(ni);
#pragma unroll
    for (int ni = 0; ni < 4; ++ni)
#pragma unroll
        for (int mi = 0; mi < 2; ++mi)
            acc[mi][ni] = __builtin_amdgcn_mfma_f32_16x16x32_f16(w1f[mi], bfr[ni], bias1[mi], 0, 0, 0);
#pragma unroll
    for (int mi = 0; mi < 2; ++mi)
#pragma unroll
        for (int ni = 0; ni < 4; ++ni) {
            f32x4 h = acc[mi][ni];
#pragma unroll
            for (int r = 0; r < 4; ++r) h[r] = fmaxf(h[r], 0.0f);
            writeH(mi, ni, h);
        }

    // ---- layer 2: C2[32,64] = W2·H1 + b2, relu ----
#pragma unroll
    for (int ni = 0; ni < 4; ++ni) bfr[ni] = readB(ni);
#pragma unroll
    for (int ni = 0; ni < 4; ++ni)
#pragma unroll
        for (int mi = 0; mi < 2; ++mi)
            acc[mi][ni] = __builtin_amdgcn_mfma_f32_16x16x32_f16(w2f[mi], bfr[ni], bias2[mi], 0, 0, 0);
#pragma unroll
    for (int mi = 0; mi < 2; ++mi)
#pragma unroll
        for (int ni = 0; ni < 4; ++ni) {
            f32x4 h = acc[mi][ni];
#pragma unroll
            for (int r = 0; r < 4; ++r) h[r] = fmaxf(h[r], 0.0f);
            writeH(mi, ni, h);
        }

    // ---- layer 3: C3[8(pad16),64] = W3·H2 + b3 ----
    f32x4 acc3[4];
#pragma unroll
    for (int ni = 0; ni < 4; ++ni) bfr[ni] = readB(ni);
#pragma unroll
    for (int ni = 0; ni < 4; ++ni)
        acc3[ni] = __builtin_amdgcn_mfma_f32_16x16x32_f16(w3f, bfr[ni], bias3, 0, 0, 0);

    const float g = growth[0];  // GROWTH_BOOST == 1.0
    const float ratio = (float)(*alive_cnt) * (1.0f / 4194304.0f);
    const float boost = (ratio < 0.2f && nalive > 0) ? 0.2f : 0.0f;

    // ---- dx back to lane=pixel via spare scratch cols 32..39 (fp16) ----
    if (lq < 2) {
#pragma unroll
        for (int ni = 0; ni < 4; ++ni) {
            int row = ni * 16 + lm;
            h16x4 v;
#pragma unroll
            for (int r = 0; r < 4; ++r) v[r] = (_Float16)(acc3[ni][r] * g);
            *(h16x4*)(base + row * SS + 32 + lq * 4) = v;
        }
    }
    h16x8 dxv = *(const h16x8*)(base + ln * SS + 32);

    float* ob = out + (size_t)b * kBS + (h0 + wv) * kW + (w0 + ln);
#pragma unroll
    for (int c = 0; c < 8; ++c) {
        float v = pc[c] + (float)dxv[c] + ((c == 3) ? boost : 0.0f);
        const float lo = (c == 3) ? 0.0f : -1.0f;
        v = fminf(fmaxf(v, lo), 1.0f);
        ob[c * kHW] = v;
    }
}

}  // namespace

extern "C" void kernel_launch(void* const* d_in, const int* in_sizes, int n_in,
                              void* d_out, int out_size, void* d_ws, size_t ws_size,
                              hipStream_t stream) {
    const float* x  = (const float*)d_in[0];
    const float* w1 = (const float*)d_in[1];
    const float* b1 = (const float*)d_in[2];
    const float* w2 = (const float*)d_in[3];
    const float* b2 = (const float*)d_in[4];
    const float* w3 = (const float*)d_in[5];
    const float* b3 = (const float*)d_in[6];
    const float* gr = (const float*)d_in[7];
    float* out = (float*)d_out;
    int* cnt = (int*)d_ws;  // ws re-poisoned 0xAA each launch -> must zero

    hipMemsetAsync(cnt, 0, sizeof(int), stream);
    alive_count_kernel<<<256, 256, 0, stream>>>(x, cnt);
    dim3 grid(kW / TW, kH / TH, kB);
    nca_fused_kernel<<<grid, 256, 0, stream>>>(x, w1, b1, w2, b2, w3, b3, gr, cnt, out);
}